// Round 1
// 256.073 us; speedup vs baseline: 1.0603x; 1.0603x over previous
//
#include <hip/hip_runtime.h>
#include <stdint.h>

#define S_LEN 2048
#define DIM   1024
#define NH    16
#define HD    64
#define BATCH 4
#define M_ROWS (BATCH * S_LEN)  // 8192

typedef __attribute__((ext_vector_type(8))) __bf16 bf16x8;
typedef __attribute__((ext_vector_type(4))) float  f32x4;

union Frag { bf16x8 v; uint4 q; };

__device__ __forceinline__ ushort f2bf(float f) {
  union { float f; unsigned u; } x; x.f = f;
  unsigned r = x.u + 0x7fffu + ((x.u >> 16) & 1u);  // RNE
  return (ushort)(r >> 16);
}
// native cast (v_cvt_pk_bf16_f32 when paired)
__device__ __forceinline__ ushort f2bf_n(float f) {
  union { __bf16 b; ushort u; } x; x.b = (__bf16)f; return x.u;
}

__device__ __forceinline__ f32x4 mfma16(const Frag& a, const Frag& b, f32x4 c) {
  return __builtin_amdgcn_mfma_f32_16x16x32_bf16(a.v, b.v, c, 0, 0, 0);
}

// async global->LDS, 16B per lane; LDS dest = wave-uniform base + lane*16
__device__ __forceinline__ void gld_lds16(const ushort* g, ushort* l) {
  __builtin_amdgcn_global_load_lds(
      (__attribute__((address_space(1))) void*)g,
      (__attribute__((address_space(3))) void*)l, 16, 0, 0);
}

// ---------------- casts ----------------
__global__ void cast_x_kernel(const float* __restrict__ src, ushort* __restrict__ dst) {
  int i = blockIdx.x * 256 + threadIdx.x;
  float4 f = ((const float4*)src)[i];
  ushort4 u; u.x = f2bf(f.x); u.y = f2bf(f.y); u.z = f2bf(f.z); u.w = f2bf(f.w);
  ((ushort4*)dst)[i] = u;
}

__global__ void cast_w_kernel(const float* __restrict__ w0, const float* __restrict__ w1,
                              const float* __restrict__ w2, const float* __restrict__ w3,
                              ushort* __restrict__ d0, ushort* __restrict__ d1,
                              ushort* __restrict__ d2, ushort* __restrict__ d3) {
  const float* s; ushort* d;
  int z = blockIdx.y;
  if (z == 0) { s = w0; d = d0; } else if (z == 1) { s = w1; d = d1; }
  else if (z == 2) { s = w2; d = d2; } else { s = w3; d = d3; }
  int i = blockIdx.x * 256 + threadIdx.x;
  float4 f = ((const float4*)s)[i];
  ushort4 u; u.x = f2bf(f.x); u.y = f2bf(f.y); u.z = f2bf(f.z); u.w = f2bf(f.w);
  ((ushort4*)d)[i] = u;
}

// ---------------- 128x128 bt-GEMM, BK=64, XOR-swizzled LDS ----------------
// MODE 0: fused QKV.  grid (24,64): wsel=blockIdx.x>>3 picks Wq/Wk/Wv; writes
//         Q (scaled, [B,H,S,HD]) / K ([B,H,S,HD]) / V^T ([B,H,HD,S]).
// MODE 1: out-proj.   grid (8,64): f32 store out[m*DIM+e] + bias[e].
template <int MODE>
__global__ __launch_bounds__(256)
void gemm_bk64(const ushort* __restrict__ A,
               const ushort* __restrict__ B0, const ushort* __restrict__ B1,
               const ushort* __restrict__ B2,
               ushort* __restrict__ Qb, ushort* __restrict__ Kb, ushort* __restrict__ Vtb,
               float* __restrict__ outf, const float* __restrict__ bias, float scaleq) {
  __shared__ __align__(16) ushort As[128 * 64];
  __shared__ __align__(16) ushort Bs[128 * 64];
  const int K = DIM;
  int lane = threadIdx.x & 63, wave = threadIdx.x >> 6;
  int quad = lane >> 4, l15 = lane & 15;
  int rowBase = blockIdx.y * 128;
  int wsel, colBase;
  const ushort* Bt;
  if (MODE == 0) {
    wsel = blockIdx.x >> 3;
    colBase = (blockIdx.x & 7) * 128;
    Bt = (wsel == 0) ? B0 : (wsel == 1) ? B1 : B2;
  } else {
    wsel = 0;
    colBase = blockIdx.x * 128;
    Bt = B0;
  }
  int wm = (wave >> 1) * 64, wn = (wave & 1) * 64;

  const ushort* Ag = A + (size_t)rowBase * K;
  const ushort* Bg = Bt + (size_t)colBase * K;

  f32x4 acc[4][4];
#pragma unroll
  for (int i = 0; i < 4; i++)
#pragma unroll
    for (int j = 0; j < 4; j++) acc[i][j] = (f32x4){0.f, 0.f, 0.f, 0.f};

  for (int k0 = 0; k0 < K; k0 += 64) {
#pragma unroll
    for (int cc = 0; cc < 4; ++cc) {
      int c = wave * 4 + cc;                 // 16 chunks of 64 slots
      int s = c * 64 + lane;                 // 16B slot id in [0,1024)
      int row = s >> 3;
      int c8 = (s & 7) ^ (row & 7);          // swizzled chunk
      gld_lds16(Ag + (size_t)row * K + k0 + c8 * 8, &As[c * 512]);
      gld_lds16(Bg + (size_t)row * K + k0 + c8 * 8, &Bs[c * 512]);
    }
    __syncthreads();
    Frag af[4][2], bf[4][2];
#pragma unroll
    for (int t = 0; t < 4; t++) {
      int ar = wm + t * 16 + l15;
      int br = wn + t * 16 + l15;
#pragma unroll
      for (int kk = 0; kk < 2; kk++) {
        af[t][kk].q = *(const uint4*)&As[ar * 64 + (((kk * 4 + quad) ^ (ar & 7))) * 8];
        bf[t][kk].q = *(const uint4*)&Bs[br * 64 + (((kk * 4 + quad) ^ (br & 7))) * 8];
      }
    }
#pragma unroll
    for (int kk = 0; kk < 2; kk++)
#pragma unroll
      for (int i = 0; i < 4; i++)
#pragma unroll
        for (int j = 0; j < 4; j++) acc[i][j] = mfma16(af[i][kk], bf[j][kk], acc[i][j]);
    __syncthreads();
  }

#pragma unroll
  for (int i = 0; i < 4; i++) {
    int rowt = wm + i * 16 + quad * 4;
#pragma unroll
    for (int j = 0; j < 4; j++) {
      int e = colBase + wn + j * 16 + l15;  // within [0,1024)
      if (MODE == 0) {
        int h = e >> 6, hd = e & 63;
        if (wsel < 2) {
          ushort* dst = wsel ? Kb : Qb;
          float sc = wsel ? 1.f : scaleq;
#pragma unroll
          for (int r = 0; r < 4; r++) {
            int m = rowBase + rowt + r;
            int b = m >> 11, s = m & (S_LEN - 1);
            dst[((size_t)((b * NH + h) * S_LEN + s) << 6) + hd] = f2bf(acc[i][j][r] * sc);
          }
        } else {
          int m0 = rowBase + rowt;
          int b = m0 >> 11, s0 = m0 & (S_LEN - 1);
          ushort4 u;
          u.x = f2bf(acc[i][j][0]); u.y = f2bf(acc[i][j][1]);
          u.z = f2bf(acc[i][j][2]); u.w = f2bf(acc[i][j][3]);
          *(ushort4*)&Vtb[((size_t)((b * NH + h) * HD + hd) << 11) + s0] = u;
        }
      } else {
        float bv = bias[e];
#pragma unroll
        for (int r = 0; r < 4; r++) {
          int m = rowBase + rowt + r;
          outf[(size_t)m * DIM + e] = acc[i][j][r] + bv;
        }
      }
    }
  }
}

// ---------------- flash attention (causal; S^T orientation; no-max streaming softmax) ----------------
// v2: double-buffered K/V async staging (T3 minimal 2-phase): loads for kt+1
// are issued BEFORE computing kt, and there is exactly ONE __syncthreads per
// iteration (its implicit vmcnt(0) drain lands after a full compute phase, so
// the global->LDS latency is hidden instead of exposed every iteration).
// LDS = 2*16K (K) + 2*16K (V) + 16K (P) = 80 KiB exactly -> 2 blocks/CU.
// P buffer is un-padded [16][128] with XOR swizzle (idx ^ ((l15&7)<<3)):
// bijective per row, bank-uniform for the b64 writes and b128 reads.
// V fragments are shared across both q sub-tiles (pf for both its kept in
// registers) -> 16 fewer ds_read_b128 per iteration.
// grid (B*H, S/128); qt = 15 - blockIdx.y (heavy tiles first).
__global__ __launch_bounds__(256, 2)
void flash_attn(const ushort* __restrict__ Qb, const ushort* __restrict__ Kb,
                const ushort* __restrict__ Vtb, ushort* __restrict__ Ctx) {
  __shared__ __align__(16) ushort Ks[2][128 * 64];   // K tiles (buf1 also Q staging)
  __shared__ __align__(16) ushort Vs[2][64 * 128];   // V^T tiles
  __shared__ __align__(16) ushort Ps[4][16 * 128];   // per-wave P slice (XOR-swizzled)

  int lane = threadIdx.x & 63, wave = threadIdx.x >> 6;
  int quad = lane >> 4, l15 = lane & 15;
  int bh = blockIdx.x;
  int qt = (gridDim.y - 1) - blockIdx.y;
  int q0 = qt * 128, wq0 = wave * 32;

  const ushort* Qh = Qb + (size_t)bh * S_LEN * HD;
  const ushort* Kh = Kb + (size_t)bh * S_LEN * HD;
  const ushort* Vh = Vtb + (size_t)bh * HD * S_LEN;

  // ---- prologue: Q tile -> Ks[1], tile kt=0 -> Ks[0]/Vs[0] (all async)
#pragma unroll
  for (int cc = 0; cc < 4; ++cc) {
    int c = wave * 4 + cc;
    int s = c * 64 + lane;
    int krow = s >> 3, kc8 = (s & 7) ^ (krow & 7);
    int vrow = s >> 4, vc8 = (s & 15) ^ (vrow & 15);
    gld_lds16(Qh + (size_t)(q0 + krow) * HD + kc8 * 8, &Ks[1][c * 512]);
    gld_lds16(Kh + (size_t)krow * HD + kc8 * 8, &Ks[0][c * 512]);
    gld_lds16(Vh + (size_t)vrow * S_LEN + vc8 * 8, &Vs[0][c * 512]);
  }
  __syncthreads();

  Frag qf[2][2];  // B-frag: B[d][qrow]
#pragma unroll
  for (int it = 0; it < 2; ++it)
#pragma unroll
    for (int ks = 0; ks < 2; ++ks) {
      int row = wq0 + it * 16 + l15;
      int c8 = (ks * 4 + quad) ^ (row & 7);
      qf[it][ks].q = *(const uint4*)&Ks[1][row * 64 + c8 * 8];
    }
  __syncthreads();  // all waves' qf reads done before kt=0 stages kt=1 into Ks[1]

  float lst[2] = {0.f, 0.f};
  f32x4 oacc[2][4];
#pragma unroll
  for (int it = 0; it < 2; ++it)
#pragma unroll
    for (int dt = 0; dt < 4; ++dt) oacc[it][dt] = (f32x4){0.f, 0.f, 0.f, 0.f};

  ushort* Pw = Ps[wave];
  const int psw = (l15 & 7) << 3;  // P XOR swizzle (ushort-index units)

  int cur = 0;
  for (int kt = 0; kt <= qt; ++kt) {
    // ---- issue next tile's loads first (latency hides under this tile's compute)
    if (kt < qt) {
#pragma unroll
      for (int cc = 0; cc < 4; ++cc) {
        int c = wave * 4 + cc;
        int s = c * 64 + lane;
        int krow = s >> 3, kc8 = (s & 7) ^ (krow & 7);
        int vrow = s >> 4, vc8 = (s & 15) ^ (vrow & 15);
        gld_lds16(Kh + (size_t)((kt + 1) * 128 + krow) * HD + kc8 * 8, &Ks[cur ^ 1][c * 512]);
        gld_lds16(Vh + (size_t)vrow * S_LEN + (kt + 1) * 128 + vc8 * 8, &Vs[cur ^ 1][c * 512]);
      }
    }
    const ushort* Kc = Ks[cur];
    const ushort* Vc = Vs[cur];

    // ---- S^T = K · Q^T
    f32x4 sacc[2][8];
    __builtin_amdgcn_s_setprio(1);
#pragma unroll
    for (int jt = 0; jt < 8; ++jt) {
      int row = jt * 16 + l15;
      Frag kf0, kf1;
      kf0.q = *(const uint4*)&Kc[row * 64 + ((quad ^ (row & 7))) * 8];
      kf1.q = *(const uint4*)&Kc[row * 64 + (((4 + quad) ^ (row & 7))) * 8];
#pragma unroll
      for (int it = 0; it < 2; ++it) {
        f32x4 a = (f32x4){0.f, 0.f, 0.f, 0.f};
        a = mfma16(kf0, qf[it][0], a);
        a = mfma16(kf1, qf[it][1], a);
        sacc[it][jt] = a;
      }
    }
    __builtin_amdgcn_s_setprio(0);

    // ---- causal mask on the diagonal tile only
    if (kt == qt) {
#pragma unroll
      for (int it = 0; it < 2; ++it)
#pragma unroll
        for (int jt = 0; jt < 8; ++jt)
#pragma unroll
          for (int r = 0; r < 4; ++r)
            if (jt * 16 + quad * 4 + r > wq0 + it * 16 + l15)
              sacc[it][jt][r] = -1e30f;
    }

    // ---- streaming softmax (no max) for both q sub-tiles; pf kept in regs
    Frag pf[2][4];
#pragma unroll
    for (int it = 0; it < 2; ++it) {
      float ps = 0.f;
#pragma unroll
      for (int jt = 0; jt < 8; ++jt) {
        float p0 = exp2f(sacc[it][jt][0]);
        float p1 = exp2f(sacc[it][jt][1]);
        float p2 = exp2f(sacc[it][jt][2]);
        float p3 = exp2f(sacc[it][jt][3]);
        ps += (p0 + p1) + (p2 + p3);
        ushort4 u; u.x = f2bf_n(p0); u.y = f2bf_n(p1); u.z = f2bf_n(p2); u.w = f2bf_n(p3);
        *(ushort4*)&Pw[l15 * 128 + ((jt * 16 + quad * 4) ^ psw)] = u;
      }
      ps += __shfl_xor(ps, 16);
      ps += __shfl_xor(ps, 32);
      lst[it] += ps;
      // P A-frags (same-wave LDS RAW; DS pipe is in-order per wave)
#pragma unroll
      for (int ks = 0; ks < 4; ++ks)
        pf[it][ks].q = *(const uint4*)&Pw[l15 * 128 + ((ks * 32 + quad * 8) ^ psw)];
    }

    // ---- O += P V (V frags hoisted: shared across both its)
    __builtin_amdgcn_s_setprio(1);
#pragma unroll
    for (int dt = 0; dt < 4; ++dt) {
      int row = dt * 16 + l15;
      Frag vf[4];
#pragma unroll
      for (int ks = 0; ks < 4; ++ks)
        vf[ks].q = *(const uint4*)&Vc[row * 128 + (((ks * 4 + quad) ^ (row & 15))) * 8];
#pragma unroll
      for (int it = 0; it < 2; ++it) {
        f32x4 a = oacc[it][dt];
#pragma unroll
        for (int ks = 0; ks < 4; ++ks) a = mfma16(pf[it][ks], vf[ks], a);
        oacc[it][dt] = a;
      }
    }
    __builtin_amdgcn_s_setprio(0);

    __syncthreads();  // drains this wave's stage loads (issued a full phase ago)
                      // + publishes buf[cur^1]; protects buf[cur] for restage
    cur ^= 1;
  }

  // ---- epilogue: normalize by l, store C-layout rows
  int b = bh >> 4, h = bh & 15;
#pragma unroll
  for (int it = 0; it < 2; ++it) {
    float linv = 1.f / lst[it];
    float lr[4];
#pragma unroll
    for (int r = 0; r < 4; ++r) lr[r] = __shfl(linv, quad * 4 + r);
#pragma unroll
    for (int r = 0; r < 4; ++r) {
      int qg = q0 + wq0 + it * 16 + quad * 4 + r;
      size_t base = ((size_t)(b * S_LEN + qg)) * DIM + h * HD;
#pragma unroll
      for (int dt = 0; dt < 4; ++dt)
        Ctx[base + dt * 16 + l15] = f2bf_n(oacc[it][dt][r] * lr[r]);
    }
  }
}

// ---------------- launch ----------------
extern "C" void kernel_launch(void* const* d_in, const int* in_sizes, int n_in,
                              void* d_out, int out_size, void* d_ws, size_t ws_size,
                              hipStream_t stream) {
  (void)in_sizes; (void)n_in; (void)out_size; (void)ws_size;
  const float* x  = (const float*)d_in[0];
  const float* Wq = (const float*)d_in[1];
  const float* Wk = (const float*)d_in[2];
  const float* Wv = (const float*)d_in[3];
  const float* Wo = (const float*)d_in[4];
  const float* bo = (const float*)d_in[5];
  float* out = (float*)d_out;

  ushort* Xb  = (ushort*)d_ws;                     // [8192][1024]
  ushort* Wqb = Xb  + (size_t)M_ROWS * DIM;
  ushort* Wkb = Wqb + (size_t)DIM * DIM;
  ushort* Wvb = Wkb + (size_t)DIM * DIM;
  ushort* Wob = Wvb + (size_t)DIM * DIM;
  ushort* Qb  = Wob + (size_t)DIM * DIM;           // [B,H,S,HD] (pre-scaled)
  ushort* Kb  = Qb  + (size_t)M_ROWS * DIM;        // [B,H,S,HD]
  ushort* Vtb = Kb  + (size_t)M_ROWS * DIM;        // [B,H,HD,S]
  ushort* Ctx = Vtb + (size_t)M_ROWS * DIM;        // [B,S,D]

  const float SCALE_Q = 0.18033688011112042f;  // log2(e) / sqrt(HD)

  cast_x_kernel<<<dim3(M_ROWS * DIM / 1024), 256, 0, stream>>>(x, Xb);
  cast_w_kernel<<<dim3(DIM * DIM / 1024, 4), 256, 0, stream>>>(Wq, Wk, Wv, Wo, Wqb, Wkb, Wvb, Wob);

  gemm_bk64<0><<<dim3(24, 64), 256, 0, stream>>>(Xb, Wqb, Wkb, Wvb, Qb, Kb, Vtb,
                                                 nullptr, nullptr, SCALE_Q);

  flash_attn<<<dim3(BATCH * NH, S_LEN / 128), 256, 0, stream>>>(Qb, Kb, Vtb, Ctx);

  gemm_bk64<1><<<dim3(8, 64), 256, 0, stream>>>(Ctx, Wob, nullptr, nullptr, nullptr, nullptr,
                                                nullptr, out, bo, 1.0f);
}